// Round 1
// baseline (200.587 us; speedup 1.0000x reference)
//
#include <hip/hip_runtime.h>

#define N_NODES 100000
#define N_EDGES 600000
#define D_FEAT  128

// ---------------------------------------------------------------------------
// K1: z0[n] = dot(x[n,:], W[0,:]);  deg[n] = 1.0 (self loop)
// one wave (64 lanes) per node; lane l loads float2 -> 512B coalesced per wave
// ---------------------------------------------------------------------------
__global__ void k_project(const float* __restrict__ x,
                          const float* __restrict__ W,
                          float* __restrict__ z0,
                          float* __restrict__ deg) {
    int gid  = blockIdx.x * blockDim.x + threadIdx.x;
    int node = gid >> 6;
    int lane = gid & 63;
    if (node >= N_NODES) return;
    const float2* xp = (const float2*)(x + (size_t)node * D_FEAT);
    const float2* wp = (const float2*)W;
    float2 xv = xp[lane];
    float2 wv = wp[lane];
    float s = xv.x * wv.x + xv.y * wv.y;
    #pragma unroll
    for (int off = 32; off > 0; off >>= 1)
        s += __shfl_down(s, off, 64);
    if (lane == 0) {
        z0[node]  = s;
        deg[node] = 1.0f;
    }
}

// ---------------------------------------------------------------------------
// K2: deg[col[e]] += 1 for each edge (int4-vectorized)
// ---------------------------------------------------------------------------
__global__ void k_degree(const int* __restrict__ col,
                         float* __restrict__ deg) {
    int i = blockIdx.x * blockDim.x + threadIdx.x;
    int e = i * 4;
    if (e + 3 < N_EDGES) {
        int4 c = *(const int4*)(col + e);
        atomicAdd(&deg[c.x], 1.0f);
        atomicAdd(&deg[c.y], 1.0f);
        atomicAdd(&deg[c.z], 1.0f);
        atomicAdd(&deg[c.w], 1.0f);
    } else {
        for (; e < N_EDGES; ++e) atomicAdd(&deg[col[e]], 1.0f);
    }
}

// ---------------------------------------------------------------------------
// K3: dis = 1/sqrt(deg) (in place); y0 = dis*z0 (in place); t1 = y0 (self loop)
// ---------------------------------------------------------------------------
__global__ void k_norm_init(float* __restrict__ deg_dis,
                            float* __restrict__ z_y,
                            float* __restrict__ t) {
    int n = blockIdx.x * blockDim.x + threadIdx.x;
    if (n >= N_NODES) return;
    float d   = deg_dis[n];          // >= 1 always (self loop), no div-by-0
    float dis = 1.0f / sqrtf(d);
    deg_dis[n] = dis;
    float y = dis * z_y[n];
    z_y[n] = y;
    t[n]   = y;
}

// ---------------------------------------------------------------------------
// K4/K6: t[col[e]] += y[row[e]]  (int4-vectorized edge loads)
// ---------------------------------------------------------------------------
__global__ void k_scatter(const int* __restrict__ row,
                          const int* __restrict__ col,
                          const float* __restrict__ y,
                          float* __restrict__ t) {
    int i = blockIdx.x * blockDim.x + threadIdx.x;
    int e = i * 4;
    if (e + 3 < N_EDGES) {
        int4 r = *(const int4*)(row + e);
        int4 c = *(const int4*)(col + e);
        float y0 = y[r.x];
        float y1 = y[r.y];
        float y2 = y[r.z];
        float y3 = y[r.w];
        atomicAdd(&t[c.x], y0);
        atomicAdd(&t[c.y], y1);
        atomicAdd(&t[c.z], y2);
        atomicAdd(&t[c.w], y3);
    } else {
        for (; e < N_EDGES; ++e) atomicAdd(&t[col[e]], y[row[e]]);
    }
}

// ---------------------------------------------------------------------------
// K5: y1 = dis^2 * t1 (z1 = dis*t1, then pre-scale for hop 2); t2 = y1
// ---------------------------------------------------------------------------
__global__ void k_round2(const float* __restrict__ dis,
                         float* __restrict__ y,
                         float* __restrict__ t) {
    int n = blockIdx.x * blockDim.x + threadIdx.x;
    if (n >= N_NODES) return;
    float d = dis[n];
    float v = d * d * t[n];
    y[n] = v;
    t[n] = v;
}

// ---------------------------------------------------------------------------
// K7: out[n] = dis[n] * t2[n] + b
// ---------------------------------------------------------------------------
__global__ void k_final(const float* __restrict__ dis,
                        const float* __restrict__ t,
                        const float* __restrict__ b,
                        float* __restrict__ out) {
    int n = blockIdx.x * blockDim.x + threadIdx.x;
    if (n >= N_NODES) return;
    out[n] = dis[n] * t[n] + b[0];
}

extern "C" void kernel_launch(void* const* d_in, const int* in_sizes, int n_in,
                              void* d_out, int out_size, void* d_ws, size_t ws_size,
                              hipStream_t stream) {
    const float* x  = (const float*)d_in[0];
    const int*   ei = (const int*)  d_in[1];   // [2, E] -> row = ei[0:E], col = ei[E:2E]
    const float* W  = (const float*)d_in[2];
    const float* b  = (const float*)d_in[3];
    float* out = (float*)d_out;

    float* buf0 = (float*)d_ws;          // deg -> dis
    float* buf1 = buf0 + N_NODES;        // z0 -> y0 -> y1
    float* buf2 = buf1 + N_NODES;        // t1 -> t2  (scatter accumulator)

    const int* row = ei;
    const int* col = ei + N_EDGES;

    const int B = 256;
    int grid_proj = (N_NODES * 64 + B - 1) / B;       // one wave per node
    int grid_edge = (N_EDGES / 4 + B - 1) / B;        // 4 edges per thread
    int grid_node = (N_NODES + B - 1) / B;

    k_project  <<<grid_proj, B, 0, stream>>>(x, W, buf1, buf0);
    k_degree   <<<grid_edge, B, 0, stream>>>(col, buf0);
    k_norm_init<<<grid_node, B, 0, stream>>>(buf0, buf1, buf2);
    k_scatter  <<<grid_edge, B, 0, stream>>>(row, col, buf1, buf2);
    k_round2   <<<grid_node, B, 0, stream>>>(buf0, buf1, buf2);
    k_scatter  <<<grid_edge, B, 0, stream>>>(row, col, buf1, buf2);
    k_final    <<<grid_node, B, 0, stream>>>(buf0, buf2, b, out);
}